// Round 1
// baseline (546.430 us; speedup 1.0000x reference)
//
#include <hip/hip_runtime.h>
#include <cstddef>

#define TSTEPS 1024
#define NIN    49
#define HID    32
#define OUTD   10
#define XSTR   52          // x row stride in LDS floats
#define SUPERS 259         // 256 compute supers + 3 pipeline-drain supers
#define NB     2           // batch elements per block (2 chains per wave)

typedef float v2f __attribute__((ext_vector_type(2)));

template<int CTRL>
__device__ __forceinline__ float quad(float v) {
    return __int_as_float(__builtin_amdgcn_mov_dpp(__float_as_int(v), CTRL, 0xF, 0xF, true));
}
__device__ __forceinline__ float sigm(float x) {
    return __builtin_amdgcn_rcpf(1.f + __expf(-x));
}
// dual fp32 FMA: acc.xy += a.xy * b.xy   (VOP3P, one issue slot)
__device__ __forceinline__ void pkfma(v2f& acc, v2f a, v2f b) {
    asm("v_pk_fma_f32 %0, %1, %2, %0" : "+v"(acc) : "v"(a), "v"(b));
}

// read 16 floats as 8 float2 pairs via 4x ds_read_b128
#define LOADH2(BASE, H2)                                                     \
    v2f H2[8];                                                               \
    {                                                                        \
        const float4* hp_ = (const float4*)(BASE);                           \
        const float4 a_ = hp_[0], b_ = hp_[1], c_ = hp_[2], d_ = hp_[3];     \
        H2[0] = (v2f){a_.x, a_.y}; H2[1] = (v2f){a_.z, a_.w};                \
        H2[2] = (v2f){b_.x, b_.y}; H2[3] = (v2f){b_.z, b_.w};                \
        H2[4] = (v2f){c_.x, c_.y}; H2[5] = (v2f){c_.z, c_.w};                \
        H2[6] = (v2f){d_.x, d_.y}; H2[7] = (v2f){d_.z, d_.w};                \
    }

// dual-batch: 4 gates x 16-elem half-dot for TWO independent chains,
// interleaved for ILP. Per-batch op order identical to the single-batch
// version (bit-identical numerics).
#define DOTPK2(W2, HA, HB, A0,A1,A2,A3, B0,B1,B2,B3)                         \
    float A0,A1,A2,A3,B0,B1,B2,B3;                                           \
    {                                                                        \
        v2f pa0={0.f,0.f}, pa1={0.f,0.f}, pa2={0.f,0.f}, pa3={0.f,0.f};      \
        v2f pb0={0.f,0.f}, pb1={0.f,0.f}, pb2={0.f,0.f}, pb3={0.f,0.f};      \
        _Pragma("unroll")                                                    \
        for (int m_ = 0; m_ < 8; ++m_) {                                     \
            pkfma(pa0, W2[0][m_], HA[m_]); pkfma(pb0, W2[0][m_], HB[m_]);    \
            pkfma(pa1, W2[1][m_], HA[m_]); pkfma(pb1, W2[1][m_], HB[m_]);    \
            pkfma(pa2, W2[2][m_], HA[m_]); pkfma(pb2, W2[2][m_], HB[m_]);    \
            pkfma(pa3, W2[3][m_], HA[m_]); pkfma(pb3, W2[3][m_], HB[m_]);    \
        }                                                                    \
        A0 = pa0.x + pa0.y; A1 = pa1.x + pa1.y;                              \
        A2 = pa2.x + pa2.y; A3 = pa3.x + pa3.y;                              \
        B0 = pb0.x + pb0.y; B1 = pb1.x + pb1.y;                              \
        B2 = pb2.x + pb2.y; B3 = pb3.x + pb3.y;                              \
        A0 += quad<0xB1>(A0); A1 += quad<0xB1>(A1);                          \
        A2 += quad<0xB1>(A2); A3 += quad<0xB1>(A3);                          \
        B0 += quad<0xB1>(B0); B1 += quad<0xB1>(B1);                          \
        B2 += quad<0xB1>(B2); B3 += quad<0xB1>(B3);                          \
    }

// gates (i,f,g,o) -> c,h; transcendental split across the lane pair
__device__ __forceinline__ float gate_act(float s0, float s1, float s2, float s3,
                                          int gp, float& c) {
    const float inA = gp ? s2 + s2 : s0;
    const float inB = gp ? s3 : s1;
    const float sA = sigm(inA);                      // gp0: sig(i)   gp1: sig(2g)
    const float sB = sigm(inB);                      // gp0: sig(f)   gp1: sig(o)
    const float vA = gp ? fmaf(2.f, sA, -1.f) : sA;  // gp0: i_act    gp1: tanh(g)
    const float xA = quad<0xB1>(vA);
    const float xB = quad<0xB1>(sB);
    const float ig = gp ? xA : vA;
    const float fg = gp ? xB : sB;
    const float gg = gp ? vA : xA;
    const float og = gp ? sB : xB;
    c = fmaf(fg, c, ig * gg);
    return og * fmaf(2.f, sigm(c + c), -1.f);        // tanh(c) = 2*sig(2c)-1
}

extern "C" __global__ void __launch_bounds__(256, 1)
lstm_pk4x2(const float* __restrict__ x,
           const float* __restrict__ Wih0, const float* __restrict__ Whh0,
           const float* __restrict__ bih0, const float* __restrict__ bhh0,
           const float* __restrict__ Wih1, const float* __restrict__ Whh1,
           const float* __restrict__ bih1, const float* __restrict__ bhh1,
           const float* __restrict__ Wout, const float* __restrict__ bout,
           float* __restrict__ y)
{
    const int tid  = threadIdx.x;   // 0..255 = 4 waves, one role each
    const int wv   = tid >> 6;      // 0:L0  1:qdot+proj  2:L1  3:producer
    const int lane = tid & 63;

    __shared__ __align__(16) float xs[NB][2 * 16 * XSTR];   // x chunks, double buffer
    __shared__ __align__(16) float xg0[NB][16][HID][4];     // Wih0*x + b0 ring
    __shared__ __align__(16) float xg1[NB][16][HID][4];     // Wih1*h0 + b1 ring
    __shared__ __align__(16) float h0r[NB][16][HID];        // h0 ring
    __shared__ __align__(16) float h1r[NB][16][HID];        // h1 ring

    {   // zero h rings (slot 15 is h[-1] = 0)
        float* z0 = &h0r[0][0][0];
        float* z1 = &h1r[0][0][0];
        for (int i = tid; i < NB * 16 * HID; i += 256) { z0[i] = 0.f; z1[i] = 0.f; }
    }

    const float* __restrict__ xb0 = x + (size_t)blockIdx.x * NB * TSTEPS * NIN;
    const float* __restrict__ xb1 = xb0 + TSTEPS * NIN;
    float* __restrict__ yb0      = y + (size_t)blockIdx.x * NB * TSTEPS * OUTD;
    float* __restrict__ yb1      = yb0 + TSTEPS * OUTD;

    if (wv == 0) {
        // ===================== L0 recurrence (2 chains): t = 4s..4s+3 =====================
        const int j = lane >> 1, gp = lane & 1;
        v2f wh0[4][8];
#pragma unroll
        for (int g = 0; g < 4; ++g) {
            const float* wr = Whh0 + (g * HID + j) * HID + 16 * gp;
#pragma unroll
            for (int m = 0; m < 8; ++m) wh0[g][m] = (v2f){wr[2*m], wr[2*m + 1]};
        }
        float ca = 0.f, cb = 0.f;
        __builtin_amdgcn_s_setprio(1);   // chain wave
        __syncthreads();   // matches P staging
        __syncthreads();   // matches P xg0[0..3] prologue
        for (int s = 0; s < SUPERS; ++s) {
            if (s < 256) {
#pragma unroll
                for (int u = 0; u < 4; ++u) {
                    const int t = 4 * s + u;
                    LOADH2(&h0r[0][(t + 15) & 15][16 * gp], hva)
                    LOADH2(&h0r[1][(t + 15) & 15][16 * gp], hvb)
                    const float4 xga = *(const float4*)&xg0[0][t & 15][j][0];
                    const float4 xgb = *(const float4*)&xg0[1][t & 15][j][0];
                    DOTPK2(wh0, hva, hvb, a0, a1, a2, a3, b0, b1, b2, b3)
                    const float ha = gate_act(a0 + xga.x, a1 + xga.y,
                                              a2 + xga.z, a3 + xga.w, gp, ca);
                    const float hb = gate_act(b0 + xgb.x, b1 + xgb.y,
                                              b2 + xgb.z, b3 + xgb.w, gp, cb);
                    if (gp == 0) {
                        h0r[0][t & 15][j] = ha;
                        h0r[1][t & 15][j] = hb;
                    }
                }
            }
            __syncthreads();
        }
    } else if (wv == 1) {
        // ======== qdot: xg1[t]=Wih1*h0[t]+b1, t=4(s-1)+u; proj: y[t], t=4(s-3)+u ========
        const int j = lane >> 1, gp = lane & 1;
        v2f wi1[4][8];
        float b1v[4];
#pragma unroll
        for (int g = 0; g < 4; ++g) {
            const float* wr = Wih1 + (g * HID + j) * HID + 16 * gp;
#pragma unroll
            for (int m = 0; m < 8; ++m) wi1[g][m] = (v2f){wr[2*m], wr[2*m + 1]};
            b1v[g] = bih1[g * HID + j] + bhh1[g * HID + j];
        }
        // projection state (lanes 0..39): o = lane>>2, kq = lane&3
        float wo[8], bo = 0.f;
        const int po = lane >> 2, kq = lane & 3;
        if (lane < 40) {
#pragma unroll
            for (int m = 0; m < 8; ++m) wo[m] = Wout[po * HID + kq * 8 + m];
            bo = bout[po];
        } else {
#pragma unroll
            for (int m = 0; m < 8; ++m) wo[m] = 0.f;
        }
        __syncthreads();
        __syncthreads();
        for (int s = 0; s < SUPERS; ++s) {
            if (s >= 1 && s <= 256) {
#pragma unroll
                for (int u = 0; u < 4; ++u) {
                    const int t = 4 * (s - 1) + u;
                    LOADH2(&h0r[0][t & 15][16 * gp], hva)
                    LOADH2(&h0r[1][t & 15][16 * gp], hvb)
                    DOTPK2(wi1, hva, hvb, a0, a1, a2, a3, b0, b1, b2, b3)
                    if (gp == 0) {
                        float4 oa, ob;
                        oa.x = a0 + b1v[0]; oa.y = a1 + b1v[1];
                        oa.z = a2 + b1v[2]; oa.w = a3 + b1v[3];
                        ob.x = b0 + b1v[0]; ob.y = b1 + b1v[1];
                        ob.z = b2 + b1v[2]; ob.w = b3 + b1v[3];
                        *(float4*)&xg1[0][t & 15][j][0] = oa;
                        *(float4*)&xg1[1][t & 15][j][0] = ob;
                    }
                }
            }
            if (s >= 3) {
                // deferred projection: y[t] for t = 4(s-3)+u (h1 written last super)
#pragma unroll
                for (int u = 0; u < 4; ++u) {
                    const int ty = 4 * (s - 3) + u;
                    {
                        const float* hb = &h1r[0][ty & 15][kq * 8];
                        const float4 va = *(const float4*)hb;
                        const float4 vb = *(const float4*)(hb + 4);
                        float acc = wo[0]*va.x + wo[1]*va.y + wo[2]*va.z + wo[3]*va.w
                                  + wo[4]*vb.x + wo[5]*vb.y + wo[6]*vb.z + wo[7]*vb.w;
                        acc += quad<0xB1>(acc);
                        acc += quad<0x4E>(acc);
                        if (lane < 40 && kq == 0) yb0[(size_t)ty * OUTD + po] = acc + bo;
                    }
                    {
                        const float* hb = &h1r[1][ty & 15][kq * 8];
                        const float4 va = *(const float4*)hb;
                        const float4 vb = *(const float4*)(hb + 4);
                        float acc = wo[0]*va.x + wo[1]*va.y + wo[2]*va.z + wo[3]*va.w
                                  + wo[4]*vb.x + wo[5]*vb.y + wo[6]*vb.z + wo[7]*vb.w;
                        acc += quad<0xB1>(acc);
                        acc += quad<0x4E>(acc);
                        if (lane < 40 && kq == 0) yb1[(size_t)ty * OUTD + po] = acc + bo;
                    }
                }
            }
            __syncthreads();
        }
    } else if (wv == 2) {
        // ===================== L1 recurrence (2 chains): t = 4(s-2)+u =====================
        const int j = lane >> 1, gp = lane & 1;
        v2f wh1[4][8];
#pragma unroll
        for (int g = 0; g < 4; ++g) {
            const float* wr = Whh1 + (g * HID + j) * HID + 16 * gp;
#pragma unroll
            for (int m = 0; m < 8; ++m) wh1[g][m] = (v2f){wr[2*m], wr[2*m + 1]};
        }
        float ca = 0.f, cb = 0.f;
        __builtin_amdgcn_s_setprio(1);   // chain wave
        __syncthreads();
        __syncthreads();
        for (int s = 0; s < SUPERS; ++s) {
            if (s >= 2 && s <= 257) {
#pragma unroll
                for (int u = 0; u < 4; ++u) {
                    const int t = 4 * (s - 2) + u;
                    LOADH2(&h1r[0][(t + 15) & 15][16 * gp], hva)
                    LOADH2(&h1r[1][(t + 15) & 15][16 * gp], hvb)
                    const float4 xga = *(const float4*)&xg1[0][t & 15][j][0];
                    const float4 xgb = *(const float4*)&xg1[1][t & 15][j][0];
                    DOTPK2(wh1, hva, hvb, a0, a1, a2, a3, b0, b1, b2, b3)
                    const float ha = gate_act(a0 + xga.x, a1 + xga.y,
                                              a2 + xga.z, a3 + xga.w, gp, ca);
                    const float hb = gate_act(b0 + xgb.x, b1 + xgb.y,
                                              b2 + xgb.z, b3 + xgb.w, gp, cb);
                    if (gp == 0) {
                        h1r[0][t & 15][j] = ha;
                        h1r[1][t & 15][j] = hb;
                    }
                }
            }
            __syncthreads();
        }
    } else {
        // ====== producer (1 wave): xg0[t] = Wih0*x[t] + b0 for t = 4(s+1)+u, both batches ======
        // lane owns 2 gate-rows: (gA=lane>>5, jj) and (gB=gA+2, jj). Weights shared across batches.
        const int jj = lane & 31;
        const int gA = lane >> 5;        // 0..1
        const int gB = 2 + (lane >> 5);  // 2..3

        v2f wa2[24], wb2[24];
        float wa48, wb48, b0a, b0b;
        {
            const float* wra = Wih0 + (gA * HID + jj) * NIN;
            const float* wrb = Wih0 + (gB * HID + jj) * NIN;
#pragma unroll
            for (int m = 0; m < 24; ++m) {
                wa2[m] = (v2f){wra[2*m], wra[2*m + 1]};
                wb2[m] = (v2f){wrb[2*m], wrb[2*m + 1]};
            }
            wa48 = wra[48]; wb48 = wrb[48];
            b0a = bih0[gA * HID + jj] + bhh0[gA * HID + jj];
            b0b = bih0[gB * HID + jj] + bhh0[gB * HID + jj];
        }

        int laddr[13];
#pragma unroll
        for (int r = 0; r < 13; ++r) {
            const int idx = lane + r * 64;
            const int s_  = idx / NIN;
            laddr[r] = s_ * XSTR + (idx - s_ * NIN);
        }
        float xra[13], xrb[13];

        auto issue = [&](int cn) {
            const float* sa = xb0 + (size_t)cn * 16 * NIN;
            const float* sb = xb1 + (size_t)cn * 16 * NIN;
#pragma unroll
            for (int r = 0; r < 12; ++r) {
                xra[r] = sa[lane + r * 64];
                xrb[r] = sb[lane + r * 64];
            }
            if (lane < 16) { xra[12] = sa[lane + 768]; xrb[12] = sb[lane + 768]; }
        };
        auto drain = [&](int cn) {
            float* da = &xs[0][(cn & 1) * (16 * XSTR)];
            float* db = &xs[1][(cn & 1) * (16 * XSTR)];
#pragma unroll
            for (int r = 0; r < 12; ++r) {
                da[laddr[r]] = xra[r];
                db[laddr[r]] = xrb[r];
            }
            if (lane < 16) { da[laddr[12]] = xra[12]; db[laddr[12]] = xrb[12]; }
        };
        auto pdot1 = [&](int t, int b) {
            const float* xp = &xs[b][((t >> 4) & 1) * (16 * XSTR) + (t & 15) * XSTR];
            const float4* x4 = (const float4*)xp;   // wave-uniform broadcast reads
            v2f aA0 = (v2f){b0a, 0.f}, aA1 = (v2f){0.f, 0.f};
            v2f aB0 = (v2f){b0b, 0.f}, aB1 = (v2f){0.f, 0.f};
#pragma unroll
            for (int u = 0; u < 12; ++u) {
                const float4 xv = x4[u];
                const v2f xlo = (v2f){xv.x, xv.y};
                const v2f xhi = (v2f){xv.z, xv.w};
                pkfma(aA0, wa2[2*u],     xlo);
                pkfma(aA1, wa2[2*u + 1], xhi);
                pkfma(aB0, wb2[2*u],     xlo);
                pkfma(aB1, wb2[2*u + 1], xhi);
            }
            const float x48 = xp[48];
            const float a0 = fmaf(wa48, x48, (aA0.x + aA0.y) + (aA1.x + aA1.y));
            const float a2 = fmaf(wb48, x48, (aB0.x + aB0.y) + (aB1.x + aB1.y));
            xg0[b][t & 15][jj][gA] = a0;
            xg0[b][t & 15][jj][gB] = a2;
        };

        // prologue: stage chunk 0 (both batches), then produce xg0[0..3]
        issue(0);
        drain(0);
        __syncthreads();
        pdot1(0, 0); pdot1(0, 1); pdot1(1, 0); pdot1(1, 1);
        pdot1(2, 0); pdot1(2, 1); pdot1(3, 0); pdot1(3, 1);
        __syncthreads();

        for (int s = 0; s < SUPERS; ++s) {
            if (s < 255) {
                const int cn = (s >> 2) + 1;
                if ((s & 3) == 0 && cn < 64) issue(cn);
                pdot1(4 * s + 4, 0); pdot1(4 * s + 4, 1);
                pdot1(4 * s + 5, 0); pdot1(4 * s + 5, 1);
                pdot1(4 * s + 6, 0); pdot1(4 * s + 6, 1);
                pdot1(4 * s + 7, 0); pdot1(4 * s + 7, 1);
                if ((s & 3) == 2 && cn < 64) drain(cn);
            }
            __syncthreads();
        }
    }
}

extern "C" void kernel_launch(void* const* d_in, const int* in_sizes, int n_in,
                              void* d_out, int out_size, void* d_ws, size_t ws_size,
                              hipStream_t stream) {
    (void)in_sizes; (void)n_in; (void)d_ws; (void)ws_size; (void)out_size;
    const float* x    = (const float*)d_in[0];
    const float* Wih0 = (const float*)d_in[1];
    const float* Whh0 = (const float*)d_in[2];
    const float* bih0 = (const float*)d_in[3];
    const float* bhh0 = (const float*)d_in[4];
    const float* Wih1 = (const float*)d_in[5];
    const float* Whh1 = (const float*)d_in[6];
    const float* bih1 = (const float*)d_in[7];
    const float* bhh1 = (const float*)d_in[8];
    const float* Wout = (const float*)d_in[9];
    const float* bout = (const float*)d_in[10];
    float* y = (float*)d_out;

    lstm_pk4x2<<<dim3(512 / NB), dim3(256), 0, stream>>>(
        x, Wih0, Whh0, bih0, bhh0, Wih1, Whh1, bih1, bhh1, Wout, bout, y);
}